// Round 10
// baseline (127.513 us; speedup 1.0000x reference)
//
#include <hip/hip_runtime.h>
#include <stdint.h>

// Problem constants (fixed by setup_inputs)
#define NROWS 8192
#define DDIM 256
#define NSTRIPS 32         // 256-col strips
#define STRIP_COLS 256
#define BN 32              // cols per LDS tile
#define NTILES 8           // STRIP_COLS / BN
#define BM 256             // rows per block (8 waves x 32 rows)
#define NSLOT NSTRIPS

// Scores are computed directly in log2-units: e is scaled by sqrt(log2(e)/0.7)
// so acc = s*log2(e) and exp(s) == exp2(acc). Since s <= 1/0.7, exp2(acc) <= 4.17
// and per-row sums <= ~34k: no overflow, so NO log-sum-exp shift is needed at all.
#define ESCALE 1.4356159f        // sqrt(log2(e)/0.7)
#define LN2F   0.6931471806f
#define NEGBIG (-1e30f)

typedef __attribute__((ext_vector_type(8))) short short8;   // 8 bf16 = 4 VGPRs
typedef __attribute__((ext_vector_type(4))) float f32x4;    // MFMA 16x16 accumulator

typedef __attribute__((address_space(3))) void lds_void;          // LDS ptr for DMA builtin
typedef const __attribute__((address_space(1))) void gl_void;     // global ptr for DMA builtin

__device__ __forceinline__ unsigned short f2bf(float x) {   // RNE float->bf16
  unsigned int u = __float_as_uint(x);
  u += 0x7fffu + ((u >> 16) & 1u);
  return (unsigned short)(u >> 16);
}

// ---------------- Kernel 1: row L2-normalize -> scaled bf16 (+zero accv) ----------------
__global__ __launch_bounds__(256) void knorm(const float* __restrict__ emb,
                                             unsigned short* __restrict__ ebf,
                                             uint4* __restrict__ accv) {
  if (blockIdx.x == 0 && threadIdx.x == 0) *accv = (uint4){0u, 0u, 0u, 0u};
  const int wave = threadIdx.x >> 6, lane = threadIdx.x & 63;
  const int row = blockIdx.x * 4 + wave;              // one wave per row
  const float4 v = *(const float4*)(emb + row * DDIM + lane * 4);
  float ss = v.x * v.x + v.y * v.y + v.z * v.z + v.w * v.w;
#pragma unroll
  for (int off = 1; off < 64; off <<= 1) ss += __shfl_xor(ss, off, 64);
  const float sc = rsqrtf(ss) * ESCALE;
  ushort4 o;
  o.x = f2bf(v.x * sc); o.y = f2bf(v.y * sc);
  o.z = f2bf(v.z * sc); o.w = f2bf(v.w * sc);
  *(ushort4*)(ebf + row * DDIM + lane * 4) = o;
}

// ---------------- Kernel 2: fused sims + masked max / sum-of-exp ----------------
// Max-TLP configuration: 512 threads (8 waves) x 32 rows/wave = 256-row panels;
// grid (32 strips, 32 panels) = 1024 blocks -> 4 blocks/CU x 8 waves = 32 waves/CU
// = the hardware occupancy cap (R5 ran 20). R5 vs R9 proved the kernel is
// latency-bound, not work-bound: halving MFMA work moved time 3%; so raise TLP.
// LDS 2 x 16 KB double buffer; depth-1 STAGE-after-barrier prefetch (syncthreads'
// implicit vmcnt(0) only drains this tile's DMAs). B-tile reuse = 256 rows ->
// staging traffic halves vs R5. No min-waves launch bound (R4 spill lesson); no
// atomics/fences in the hot loop (R6 lesson).
__global__ __launch_bounds__(512) void kmain(const unsigned short* __restrict__ ebf,
                                             const int* __restrict__ cats,
                                             float* __restrict__ posP,
                                             float* __restrict__ sumP) {
  // B tile: BN cols x 256 k as 16B chunks, chunk p = kc*32 + col at byte p*16.
  __shared__ alignas(16) unsigned short smem[2][BN * DDIM];  // 2 x 16 KB
  const int tid = threadIdx.x;
  const int lane = tid & 63, wave = tid >> 6;
  const int lane15 = lane & 15, quad = lane >> 4;
  const int strip = blockIdx.x, rowTile = blockIdx.y;
  const int rowG = rowTile * BM + wave * 32;          // this wave's 32 rows (m=2)
  const int col0 = strip * STRIP_COLS;

  // A fragments for the whole kernel live in registers: a[m][kk] covers
  // rows rowG+m*16+(lane&15), k = kk*32 + quad*8 .. +7   (64 VGPRs)
  short8 a[2][8];
#pragma unroll
  for (int m = 0; m < 2; ++m)
#pragma unroll
    for (int kk = 0; kk < 8; ++kk)
      a[m][kk] = *(const short8*)(ebf + (rowG + m * 16 + lane15) * DDIM + kk * 32 + quad * 8);

  // Per-lane C-layout row categories: row = quad*4 + r (+ m*16)
  int cati[2][4];
#pragma unroll
  for (int m = 0; m < 2; ++m)
#pragma unroll
    for (int r = 0; r < 4; ++r)
      cati[m][r] = cats[rowG + m * 16 + quad * 4 + r];

  // Is this lane the diagonal element (row==col) within a diagonal 16x16 tile?
  bool dlr[4];
#pragma unroll
  for (int r = 0; r < 4; ++r) dlr[r] = (lane15 == quad * 4 + r);

  float pm[2][4], ns[2][4];
#pragma unroll
  for (int m = 0; m < 2; ++m)
#pragma unroll
    for (int r = 0; r < 4; ++r) { pm[m][r] = NEGBIG; ns[m][r] = 0.f; }

  // Async-stage one B tile (1024 16B chunks) into buffer `buf`: 2 DMA per thread.
  // Thread (w,l) takes chunks p = c*512 + w*64 + l; LDS byte = p*16 decomposes as
  // wave-uniform (c*8192 + w*1024) + l*16. Global: kc = c*16 + w*2 + (l>>5), col = l&31.
#define STAGE(t, buf)                                                           \
  {                                                                             \
    const unsigned short* g = ebf +                                             \
        (size_t)(col0 + (t) * BN + (lane & 31)) * DDIM +                        \
        (wave * 2 + (lane >> 5)) * 8;                                           \
    char* lb = (char*)&smem[(buf)][0] + wave * 1024;                            \
    _Pragma("unroll")                                                           \
    for (int c = 0; c < 2; ++c)                                                 \
      __builtin_amdgcn_global_load_lds((gl_void*)(g + c * 128),                 \
                                       (lds_void*)(lb + c * 8192), 16, 0, 0);   \
  }

  STAGE(0, 0);

  for (int t = 0; t < NTILES; ++t) {
    __syncthreads();                       // tile t's DMA drained; prev reads done
    if (t + 1 < NTILES) STAGE(t + 1, (t + 1) & 1);   // overlaps this tile's MFMA
    const char* bb = (const char*)&smem[t & 1][0];
    const int colBase = col0 + t * BN;
    const int cjt[2] = {cats[colBase + lane15], cats[colBase + 16 + lane15]};

#pragma unroll
    for (int nt = 0; nt < 2; ++nt) {
      // Batch the 8 B-fragment reads ahead of the MFMA cluster.
      short8 b[8];
#pragma unroll
      for (int kk = 0; kk < 8; ++kk)
        b[kk] = *(const short8*)(bb + kk * 2048 + quad * 512 + nt * 256 + lane15 * 16);
      f32x4 acc0 = {0.f, 0.f, 0.f, 0.f}, acc1 = {0.f, 0.f, 0.f, 0.f};
      __builtin_amdgcn_s_setprio(1);       // T5: favor MFMA-issuing wave
#pragma unroll
      for (int kk = 0; kk < 8; ++kk) {
        acc0 = __builtin_amdgcn_mfma_f32_16x16x32_bf16(a[0][kk], b[kk], acc0, 0, 0, 0);
        acc1 = __builtin_amdgcn_mfma_f32_16x16x32_bf16(a[1][kk], b[kk], acc1, 0, 0, 0);
      }
      __builtin_amdgcn_s_setprio(0);
      const int cj = cjt[nt];
      // Wave-uniform: does this 16x16 tile sit on the global diagonal?
      const bool dg0 = (rowG == colBase + nt * 16);
      const bool dg1 = (rowG + 16 == colBase + nt * 16);
#pragma unroll
      for (int m = 0; m < 2; ++m) {
        const bool dg = m ? dg1 : dg0;
#pragma unroll
        for (int r = 0; r < 4; ++r) {
          const float s = m ? acc1[r] : acc0[r];      // score in log2-units
          const float e = __builtin_amdgcn_exp2f(s);
          const bool same = (cj == cati[m][r]);
          float psv = same ? s : NEGBIG;              // positive candidate
          if (dg) psv = dlr[r] ? NEGBIG : psv;        // exclude self (rare branch)
          pm[m][r] = fmaxf(pm[m][r], psv);
          ns[m][r] += same ? 0.f : e;                 // negative sum-of-exp
        }
      }
    }
  }

  // Reduce across the 16 lanes of each quad (they share rows quad*4+r).
#pragma unroll
  for (int off = 1; off < 16; off <<= 1) {
#pragma unroll
    for (int m = 0; m < 2; ++m)
#pragma unroll
      for (int r = 0; r < 4; ++r) {
        pm[m][r] = fmaxf(pm[m][r], __shfl_xor(pm[m][r], off, 64));
        ns[m][r] += __shfl_xor(ns[m][r], off, 64);
      }
  }
  if (lane15 == 0) {
#pragma unroll
    for (int m = 0; m < 2; ++m)
#pragma unroll
      for (int r = 0; r < 4; ++r) {
        const int row = rowG + m * 16 + quad * 4 + r;
        posP[strip * NROWS + row] = pm[m][r];
        sumP[strip * NROWS + row] = ns[m][r];
      }
  }
}

// ---------------- Kernel 3: merge strips, per-row loss, reduce, finalize ----------------
__global__ __launch_bounds__(256) void kmerge(const float* __restrict__ posP,
                                              const float* __restrict__ sumP,
                                              float* __restrict__ acc,
                                              float* __restrict__ out) {
  const int row = blockIdx.x * 256 + threadIdx.x;
  float pm = NEGBIG, ns = 0.f;
#pragma unroll 8
  for (int s = 0; s < NSLOT; ++s) {
    pm = fmaxf(pm, posP[s * NROWS + row]);
    ns += sumP[s * NROWS + row];
  }
  const bool valid = (pm > -1e29f) && (ns > 0.f);
  // pm is pos*log2(e); loss = -pos + ln(exp2(pm) + sum_neg exp(s))   (no shift needed)
  float loss = valid ? (logf(__builtin_amdgcn_exp2f(pm) + ns) - pm * LN2F) : 0.f;
  float cnt = valid ? 1.f : 0.f;
#pragma unroll
  for (int off = 1; off < 64; off <<= 1) {
    loss += __shfl_xor(loss, off, 64);
    cnt += __shfl_xor(cnt, off, 64);
  }
  if ((threadIdx.x & 63) == 0) {
    atomicAdd(&acc[0], loss);
    atomicAdd(&acc[1], cnt);
    __threadfence();                       // my adds visible before the counter bump
  }
  __syncthreads();
  if (threadIdx.x == 0) {
    const int prev = atomicAdd((int*)(acc + 2), 1);
    if (prev == (int)gridDim.x - 1) {      // last block finalizes
      const float L = atomicAdd(&acc[0], 0.f);   // coherent reads
      const float C = atomicAdd(&acc[1], 0.f);
      out[0] = L / fmaxf(C, 1.f);
    }
  }
}

// ---------------- Launch ----------------
extern "C" void kernel_launch(void* const* d_in, const int* in_sizes, int n_in,
                              void* d_out, int out_size, void* d_ws, size_t ws_size,
                              hipStream_t stream) {
  const float* emb = (const float*)d_in[0];
  const int* cats = (const int*)d_in[1];
  // d_in[2] (font_labels) is unused by the reference.
  float* out = (float*)d_out;

  char* ws = (char*)d_ws;
  float* accv = (float*)ws;                                  // loss, cnt, block counter
  unsigned short* ebf = (unsigned short*)(ws + 256);         // 4 MB bf16 normalized
  float* posP = (float*)(ws + 256 + NROWS * DDIM * 2);       // 32 slots x 8192
  float* sumP = posP + NSLOT * NROWS;

  knorm<<<NROWS / 4, 256, 0, stream>>>(emb, ebf, (uint4*)ws);
  kmain<<<dim3(NSTRIPS, NROWS / BM), 512, 0, stream>>>(ebf, cats, posP, sumP);
  kmerge<<<NROWS / 256, 256, 0, stream>>>(posP, sumP, accv, out);
}

// Round 11
// 121.087 us; speedup vs baseline: 1.0531x; 1.0531x over previous
//
#include <hip/hip_runtime.h>
#include <stdint.h>

// Problem constants (fixed by setup_inputs)
#define NROWS 8192
#define DDIM 256
#define NSTRIPS 32         // 256-col strips
#define STRIP_COLS 256
#define BN 32              // cols per phase-pair (2 x 16)
#define NTILES 8           // STRIP_COLS / BN
#define BM 128             // rows per block (4 waves x 32 rows)
#define NSLOT NSTRIPS

// Scores are computed directly in log2-units: e is scaled by sqrt(log2(e)/0.7)
// so acc = s*log2(e) and exp(s) == exp2(acc). Since s <= 1/0.7, exp2(acc) <= 4.17
// and per-row sums <= ~34k: no overflow, so NO log-sum-exp shift is needed at all.
#define ESCALE 1.4356159f        // sqrt(log2(e)/0.7)
#define LN2F   0.6931471806f
#define NEGBIG (-1e30f)

typedef __attribute__((ext_vector_type(8))) short short8;   // 8 bf16 = 4 VGPRs
typedef __attribute__((ext_vector_type(4))) float f32x4;    // MFMA 16x16 accumulator

__device__ __forceinline__ unsigned short f2bf(float x) {   // RNE float->bf16
  unsigned int u = __float_as_uint(x);
  u += 0x7fffu + ((u >> 16) & 1u);
  return (unsigned short)(u >> 16);
}

// ---------------- Kernel 1: row L2-normalize -> scaled bf16, two layouts ----------------
// Row-major ebf (A-fragment loads) AND chunk-major ebfB: 16B chunk (8 k-values) of
// column `col` at ushort offset (kc*NROWS + col)*8. kmain's B-fragment load then
// reads 256B contiguous per quad straight from global -- no LDS staging at all.
__global__ __launch_bounds__(256) void knorm(const float* __restrict__ emb,
                                             unsigned short* __restrict__ ebf,
                                             unsigned short* __restrict__ ebfB,
                                             uint4* __restrict__ accv) {
  if (blockIdx.x == 0 && threadIdx.x == 0) *accv = (uint4){0u, 0u, 0u, 0u};
  const int wave = threadIdx.x >> 6, lane = threadIdx.x & 63;
  const int row = blockIdx.x * 4 + wave;              // one wave per row
  const float4 v = *(const float4*)(emb + row * DDIM + lane * 4);
  float ss = v.x * v.x + v.y * v.y + v.z * v.z + v.w * v.w;
#pragma unroll
  for (int off = 1; off < 64; off <<= 1) ss += __shfl_xor(ss, off, 64);
  const float sc = rsqrtf(ss) * ESCALE;
  ushort4 o;
  o.x = f2bf(v.x * sc); o.y = f2bf(v.y * sc);
  o.z = f2bf(v.z * sc); o.w = f2bf(v.w * sc);
  *(ushort4*)(ebf + row * DDIM + lane * 4) = o;                       // row-major
  // chunk-major: lane holds k = lane*4..lane*4+3 -> chunk kc = lane>>1,
  // half-chunk (lane&1): 8B store at (kc*NROWS + row)*8 ushorts + (lane&1)*4.
  *(ushort4*)(ebfB + ((lane >> 1) * NROWS + row) * 8 + (lane & 1) * 4) = o;
}

// ---------------- Kernel 2: fused sims + masked max / sum-of-exp, BARRIER-FREE ----------------
// R5/R9/R10 localized the bound to the per-tile barrier lockstep (work halved: -3%;
// TLP raised: -14%; all pipes <28% busy). This version deletes the synchronization
// entirely: B fragments are loaded per-wave directly from the chunk-major ebfB
// (256B contiguous per quad, L2-resident), so there is NO LDS, NO __syncthreads,
// and every wave runs the whole K-loop independently. grid (32 strips, 64 panels)
// = 2048 blocks x 4 waves; strip = blockIdx.x%8-steered to a fixed XCD so each
// XCD's L2 re-serves its strips' B. No min-waves bound (R4 spill lesson); no
// atomics/fences in the hot loop (R6 lesson).
__global__ __launch_bounds__(256) void kmain(const unsigned short* __restrict__ ebf,
                                             const unsigned short* __restrict__ ebfB,
                                             const int* __restrict__ cats,
                                             float* __restrict__ posP,
                                             float* __restrict__ sumP) {
  const int tid = threadIdx.x;
  const int lane = tid & 63, wave = tid >> 6;
  const int lane15 = lane & 15, quad = lane >> 4;
  const int strip = blockIdx.x, rowTile = blockIdx.y;
  const int rowG = rowTile * BM + wave * 32;          // this wave's 32 rows (m=2)
  const int col0 = strip * STRIP_COLS;

  // A fragments for the whole kernel live in registers: a[m][kk] covers
  // rows rowG+m*16+(lane&15), k = kk*32 + quad*8 .. +7   (64 VGPRs)
  short8 a[2][8];
#pragma unroll
  for (int m = 0; m < 2; ++m)
#pragma unroll
    for (int kk = 0; kk < 8; ++kk)
      a[m][kk] = *(const short8*)(ebf + (rowG + m * 16 + lane15) * DDIM + kk * 32 + quad * 8);

  // Per-lane C-layout row categories: row = quad*4 + r (+ m*16)
  int cati[2][4];
#pragma unroll
  for (int m = 0; m < 2; ++m)
#pragma unroll
    for (int r = 0; r < 4; ++r)
      cati[m][r] = cats[rowG + m * 16 + quad * 4 + r];

  // Is this lane the diagonal element (row==col) within a diagonal 16x16 tile?
  bool dlr[4];
#pragma unroll
  for (int r = 0; r < 4; ++r) dlr[r] = (lane15 == quad * 4 + r);

  float pm[2][4], ns[2][4];
#pragma unroll
  for (int m = 0; m < 2; ++m)
#pragma unroll
    for (int r = 0; r < 4; ++r) { pm[m][r] = NEGBIG; ns[m][r] = 0.f; }

  // B-fragment base (ushort index): chunk (kc = kk*4+quad, col) at (kc*NROWS+col)*8.
  const unsigned short* bbase = ebfB + ((size_t)quad * NROWS + col0 + lane15) * 8;

  for (int t = 0; t < NTILES; ++t) {
#pragma unroll
    for (int nt = 0; nt < 2; ++nt) {
      const int colBase = col0 + t * BN + nt * 16;
      // 8 independent coalesced 16B loads (per quad: 16 lanes x 16B = 256B line-
      // aligned run). No barrier anywhere -- loads of the next phase overlap the
      // MFMA + epilogue of this one across/within waves.
      short8 b[8];
#pragma unroll
      for (int kk = 0; kk < 8; ++kk)
        b[kk] = *(const short8*)(bbase + ((size_t)kk * 4 * NROWS + t * BN + nt * 16) * 8);
      f32x4 acc0 = {0.f, 0.f, 0.f, 0.f}, acc1 = {0.f, 0.f, 0.f, 0.f};
      __builtin_amdgcn_s_setprio(1);       // T5: favor MFMA-issuing wave
#pragma unroll
      for (int kk = 0; kk < 8; ++kk) {
        acc0 = __builtin_amdgcn_mfma_f32_16x16x32_bf16(a[0][kk], b[kk], acc0, 0, 0, 0);
        acc1 = __builtin_amdgcn_mfma_f32_16x16x32_bf16(a[1][kk], b[kk], acc1, 0, 0, 0);
      }
      __builtin_amdgcn_s_setprio(0);
      const int cj = cats[colBase + lane15];
      // Wave-uniform: does this 16x16 tile sit on the global diagonal?
      const bool dg0 = (rowG == colBase);
      const bool dg1 = (rowG + 16 == colBase);
#pragma unroll
      for (int m = 0; m < 2; ++m) {
        const bool dg = m ? dg1 : dg0;
#pragma unroll
        for (int r = 0; r < 4; ++r) {
          const float s = m ? acc1[r] : acc0[r];      // score in log2-units
          const float e = __builtin_amdgcn_exp2f(s);
          const bool same = (cj == cati[m][r]);
          float psv = same ? s : NEGBIG;              // positive candidate
          if (dg) psv = dlr[r] ? NEGBIG : psv;        // exclude self (rare branch)
          pm[m][r] = fmaxf(pm[m][r], psv);
          ns[m][r] += same ? 0.f : e;                 // negative sum-of-exp
        }
      }
    }
  }

  // Reduce across the 16 lanes of each quad (they share rows quad*4+r).
#pragma unroll
  for (int off = 1; off < 16; off <<= 1) {
#pragma unroll
    for (int m = 0; m < 2; ++m)
#pragma unroll
      for (int r = 0; r < 4; ++r) {
        pm[m][r] = fmaxf(pm[m][r], __shfl_xor(pm[m][r], off, 64));
        ns[m][r] += __shfl_xor(ns[m][r], off, 64);
      }
  }
  if (lane15 == 0) {
#pragma unroll
    for (int m = 0; m < 2; ++m)
#pragma unroll
      for (int r = 0; r < 4; ++r) {
        const int row = rowG + m * 16 + quad * 4 + r;
        posP[strip * NROWS + row] = pm[m][r];
        sumP[strip * NROWS + row] = ns[m][r];
      }
  }
}

// ---------------- Kernel 3: merge strips, per-row loss, reduce, finalize ----------------
__global__ __launch_bounds__(256) void kmerge(const float* __restrict__ posP,
                                              const float* __restrict__ sumP,
                                              float* __restrict__ acc,
                                              float* __restrict__ out) {
  const int row = blockIdx.x * 256 + threadIdx.x;
  float pm = NEGBIG, ns = 0.f;
#pragma unroll 8
  for (int s = 0; s < NSLOT; ++s) {
    pm = fmaxf(pm, posP[s * NROWS + row]);
    ns += sumP[s * NROWS + row];
  }
  const bool valid = (pm > -1e29f) && (ns > 0.f);
  // pm is pos*log2(e); loss = -pos + ln(exp2(pm) + sum_neg exp(s))   (no shift needed)
  float loss = valid ? (logf(__builtin_amdgcn_exp2f(pm) + ns) - pm * LN2F) : 0.f;
  float cnt = valid ? 1.f : 0.f;
#pragma unroll
  for (int off = 1; off < 64; off <<= 1) {
    loss += __shfl_xor(loss, off, 64);
    cnt += __shfl_xor(cnt, off, 64);
  }
  if ((threadIdx.x & 63) == 0) {
    atomicAdd(&acc[0], loss);
    atomicAdd(&acc[1], cnt);
    __threadfence();                       // my adds visible before the counter bump
  }
  __syncthreads();
  if (threadIdx.x == 0) {
    const int prev = atomicAdd((int*)(acc + 2), 1);
    if (prev == (int)gridDim.x - 1) {      // last block finalizes
      const float L = atomicAdd(&acc[0], 0.f);   // coherent reads
      const float C = atomicAdd(&acc[1], 0.f);
      out[0] = L / fmaxf(C, 1.f);
    }
  }
}

// ---------------- Launch ----------------
extern "C" void kernel_launch(void* const* d_in, const int* in_sizes, int n_in,
                              void* d_out, int out_size, void* d_ws, size_t ws_size,
                              hipStream_t stream) {
  const float* emb = (const float*)d_in[0];
  const int* cats = (const int*)d_in[1];
  // d_in[2] (font_labels) is unused by the reference.
  float* out = (float*)d_out;

  char* ws = (char*)d_ws;
  float* accv = (float*)ws;                                  // loss, cnt, block counter
  unsigned short* ebf = (unsigned short*)(ws + 256);         // 4 MB row-major bf16
  unsigned short* ebfB = ebf + (size_t)NROWS * DDIM;         // 4 MB chunk-major bf16
  float* posP = (float*)(ws + 256 + 2 * (size_t)NROWS * DDIM * 2);  // 32 slots x 8192
  float* sumP = posP + NSLOT * NROWS;

  knorm<<<NROWS / 4, 256, 0, stream>>>(emb, ebf, ebfB, (uint4*)ws);
  kmain<<<dim3(NSTRIPS, NROWS / BM), 256, 0, stream>>>(ebf, ebfB, cats, posP, sumP);
  kmerge<<<NROWS / 256, 256, 0, stream>>>(posP, sumP, accv, out);
}

// Round 14
// 114.827 us; speedup vs baseline: 1.1105x; 1.0545x over previous
//
#include <hip/hip_runtime.h>
#include <stdint.h>

// Problem constants (fixed by setup_inputs)
#define NROWS 8192
#define DDIM 256
#define NSTRIPS 32         // 256-col strips
#define STRIP_COLS 256
#define BN 32              // cols per t-iteration (2 phases x 16)
#define NTILES 8           // STRIP_COLS / BN
#define BM 128             // rows per block (4 waves x 32 rows)
#define NSLOT NSTRIPS

// Scores are computed directly in log2-units: e is scaled by sqrt(log2(e)/0.7)
// so acc = s*log2(e) and exp(s) == exp2(acc). Since s <= 1/0.7, exp2(acc) <= 4.17
// and per-row sums <= ~34k: no overflow, so NO log-sum-exp shift is needed at all.
#define ESCALE 1.4356159f        // sqrt(log2(e)/0.7)
#define LN2F   0.6931471806f
#define NEGBIG (-1e30f)

typedef __attribute__((ext_vector_type(8))) short short8;   // 8 bf16 = 4 VGPRs
typedef __attribute__((ext_vector_type(4))) float f32x4;    // MFMA 16x16 accumulator

__device__ __forceinline__ unsigned short f2bf(float x) {   // RNE float->bf16
  unsigned int u = __float_as_uint(x);
  u += 0x7fffu + ((u >> 16) & 1u);
  return (unsigned short)(u >> 16);
}

// ---------------- Kernel 1: row L2-normalize -> scaled bf16, chunk-major only ----------------
// ebfB layout: 16B chunk (8 k-values) of row `row` at ushort offset (kc*NROWS+row)*8,
// kc = k/8. BOTH A- and B-fragments of kmain read this layout (16B contiguous per
// lane, 256B per quad) -- the row-major copy is gone, halving knorm's writes.
__global__ __launch_bounds__(256) void knorm(const float* __restrict__ emb,
                                             unsigned short* __restrict__ ebfB,
                                             uint4* __restrict__ accv) {
  if (blockIdx.x == 0 && threadIdx.x == 0) *accv = (uint4){0u, 0u, 0u, 0u};
  const int wave = threadIdx.x >> 6, lane = threadIdx.x & 63;
  const int row = blockIdx.x * 4 + wave;              // one wave per row
  const float4 v = *(const float4*)(emb + row * DDIM + lane * 4);
  float ss = v.x * v.x + v.y * v.y + v.z * v.z + v.w * v.w;
#pragma unroll
  for (int off = 1; off < 64; off <<= 1) ss += __shfl_xor(ss, off, 64);
  const float sc = rsqrtf(ss) * ESCALE;
  ushort4 o;
  o.x = f2bf(v.x * sc); o.y = f2bf(v.y * sc);
  o.z = f2bf(v.z * sc); o.w = f2bf(v.w * sc);
  // lane holds k = lane*4 .. lane*4+3 -> chunk kc = lane>>1, half (lane&1).
  *(ushort4*)(ebfB + ((lane >> 1) * NROWS + row) * 8 + (lane & 1) * 4) = o;
}

// ---------------- Kernel 2: fused sims, barrier-free + software-pipelined ----------------
// R5..R11 localized the bound: not work (R9), not TLP (R10), not barriers/LDS (R11)
// -- it is L2 LATENCY in front of each MFMA cluster (38us with both pipes idle,
// ~2 waves/SIMD effective). Fix: per-wave ILP. Named double buffers b0/b1 (no
// runtime indexing -> no scratch); each phase's 8 loads are issued BEFORE the
// previous phase's MFMA+epilogue (~270 cyc of cover vs 0). No LDS, no barriers,
// no setprio (homogeneous waves: m190 says ~0/negative). No min-waves bound
// (R4 spill lesson); no atomics/fences in the hot loop (R6 lesson).
__global__ __launch_bounds__(256) void kmain(const unsigned short* __restrict__ ebfB,
                                             const int* __restrict__ cats,
                                             float* __restrict__ posP,
                                             float* __restrict__ sumP) {
  const int tid = threadIdx.x;
  const int lane = tid & 63;
  const int lane15 = lane & 15, quad = lane >> 4;
  const int wave = tid >> 6;
  const int strip = blockIdx.x, rowTile = blockIdx.y;
  const int rowG = rowTile * BM + wave * 32;          // this wave's 32 rows (m=2)
  const int col0 = strip * STRIP_COLS;

  // A fragments (chunk-major): a[m][kk] = rows rowG+m*16+lane15, k=kk*32+quad*8..+7.
  short8 a[2][8];
#pragma unroll
  for (int m = 0; m < 2; ++m)
#pragma unroll
    for (int kk = 0; kk < 8; ++kk)
      a[m][kk] = *(const short8*)(ebfB +
          ((size_t)(kk * 4 + quad) * NROWS + rowG + m * 16 + lane15) * 8);

  // Per-lane C-layout row categories: row = quad*4 + r (+ m*16)
  int cati[2][4];
#pragma unroll
  for (int m = 0; m < 2; ++m)
#pragma unroll
    for (int r = 0; r < 4; ++r)
      cati[m][r] = cats[rowG + m * 16 + quad * 4 + r];

  // Is this lane the diagonal element (row==col) within a diagonal 16x16 tile?
  bool dlr[4];
#pragma unroll
  for (int r = 0; r < 4; ++r) dlr[r] = (lane15 == quad * 4 + r);

  float pm[2][4], ns[2][4];
#pragma unroll
  for (int m = 0; m < 2; ++m)
#pragma unroll
    for (int r = 0; r < 4; ++r) { pm[m][r] = NEGBIG; ns[m][r] = 0.f; }

  // B-fragment base: chunk (kc = kk*4+quad, col = col0+lane15+off).
  const unsigned short* bbase = ebfB + ((size_t)quad * NROWS + col0 + lane15) * 8;

#define LOADB(buf, t, nt)                                                       \
  _Pragma("unroll")                                                             \
  for (int kk = 0; kk < 8; ++kk)                                                \
    buf[kk] = *(const short8*)(bbase +                                          \
        ((size_t)kk * 4 * NROWS + (t) * BN + (nt) * 16) * 8);

#define DOMFMA(buf, ACC0, ACC1)                                                 \
  f32x4 ACC0 = {0.f, 0.f, 0.f, 0.f}, ACC1 = {0.f, 0.f, 0.f, 0.f};              \
  _Pragma("unroll")                                                             \
  for (int kk = 0; kk < 8; ++kk) {                                              \
    ACC0 = __builtin_amdgcn_mfma_f32_16x16x32_bf16(a[0][kk], buf[kk], ACC0, 0, 0, 0); \
    ACC1 = __builtin_amdgcn_mfma_f32_16x16x32_bf16(a[1][kk], buf[kk], ACC1, 0, 0, 0); \
  }

#define EPI(ACC0, ACC1, t, nt)                                                  \
  {                                                                             \
    const int colBase = col0 + (t) * BN + (nt) * 16;                            \
    const int cj = cats[colBase + lane15];                                      \
    const bool dg0 = (rowG == colBase);                                         \
    const bool dg1 = (rowG + 16 == colBase);                                    \
    _Pragma("unroll")                                                           \
    for (int m = 0; m < 2; ++m) {                                               \
      const bool dg = m ? dg1 : dg0;                                            \
      _Pragma("unroll")                                                         \
      for (int r = 0; r < 4; ++r) {                                             \
        const float s = m ? ACC1[r] : ACC0[r];      /* score in log2-units */   \
        const float e = __builtin_amdgcn_exp2f(s);                              \
        const bool same = (cj == cati[m][r]);                                   \
        float psv = same ? s : NEGBIG;                                          \
        if (dg) psv = dlr[r] ? NEGBIG : psv;        /* exclude self (rare) */   \
        pm[m][r] = fmaxf(pm[m][r], psv);                                        \
        ns[m][r] += same ? 0.f : e;                                             \
      }                                                                         \
    }                                                                           \
  }

  short8 b0[8], b1[8];
  LOADB(b0, 0, 0);                         // prologue: phase 0 in flight

  for (int t = 0; t < NTILES; ++t) {
    LOADB(b1, t, 1);                       // issue nt=1 loads EARLY
    { DOMFMA(b0, acc0, acc1) EPI(acc0, acc1, t, 0) }   // ~270 cyc cover for b1
    if (t + 1 < NTILES) LOADB(b0, t + 1, 0);           // issue next-t loads EARLY
    { DOMFMA(b1, acc2, acc3) EPI(acc2, acc3, t, 1) }   // cover for next b0
  }

  // Reduce across the 16 lanes of each quad (they share rows quad*4+r).
#pragma unroll
  for (int off = 1; off < 16; off <<= 1) {
#pragma unroll
    for (int m = 0; m < 2; ++m)
#pragma unroll
      for (int r = 0; r < 4; ++r) {
        pm[m][r] = fmaxf(pm[m][r], __shfl_xor(pm[m][r], off, 64));
        ns[m][r] += __shfl_xor(ns[m][r], off, 64);
      }
  }
  if (lane15 == 0) {
#pragma unroll
    for (int m = 0; m < 2; ++m)
#pragma unroll
      for (int r = 0; r < 4; ++r) {
        const int row = rowG + m * 16 + quad * 4 + r;
        posP[strip * NROWS + row] = pm[m][r];
        sumP[strip * NROWS + row] = ns[m][r];
      }
  }
}

// ---------------- Kernel 3: merge strips, per-row loss, reduce, finalize ----------------
__global__ __launch_bounds__(256) void kmerge(const float* __restrict__ posP,
                                              const float* __restrict__ sumP,
                                              float* __restrict__ acc,
                                              float* __restrict__ out) {
  const int row = blockIdx.x * 256 + threadIdx.x;
  float pm = NEGBIG, ns = 0.f;
#pragma unroll 8
  for (int s = 0; s < NSLOT; ++s) {
    pm = fmaxf(pm, posP[s * NROWS + row]);
    ns += sumP[s * NROWS + row];
  }
  const bool valid = (pm > -1e29f) && (ns > 0.f);
  // pm is pos*log2(e); loss = -pos + ln(exp2(pm) + sum_neg exp(s))   (no shift needed)
  float loss = valid ? (logf(__builtin_amdgcn_exp2f(pm) + ns) - pm * LN2F) : 0.f;
  float cnt = valid ? 1.f : 0.f;
#pragma unroll
  for (int off = 1; off < 64; off <<= 1) {
    loss += __shfl_xor(loss, off, 64);
    cnt += __shfl_xor(cnt, off, 64);
  }
  if ((threadIdx.x & 63) == 0) {
    atomicAdd(&acc[0], loss);
    atomicAdd(&acc[1], cnt);
    __threadfence();                       // my adds visible before the counter bump
  }
  __syncthreads();
  if (threadIdx.x == 0) {
    const int prev = atomicAdd((int*)(acc + 2), 1);
    if (prev == (int)gridDim.x - 1) {      // last block finalizes
      const float L = atomicAdd(&acc[0], 0.f);   // coherent reads
      const float C = atomicAdd(&acc[1], 0.f);
      out[0] = L / fmaxf(C, 1.f);
    }
  }
}

// ---------------- Launch ----------------
extern "C" void kernel_launch(void* const* d_in, const int* in_sizes, int n_in,
                              void* d_out, int out_size, void* d_ws, size_t ws_size,
                              hipStream_t stream) {
  const float* emb = (const float*)d_in[0];
  const int* cats = (const int*)d_in[1];
  // d_in[2] (font_labels) is unused by the reference.
  float* out = (float*)d_out;

  char* ws = (char*)d_ws;
  float* accv = (float*)ws;                                  // loss, cnt, block counter
  unsigned short* ebfB = (unsigned short*)(ws + 256);        // 4 MB chunk-major bf16
  float* posP = (float*)(ws + 256 + (size_t)NROWS * DDIM * 2);  // 32 slots x 8192
  float* sumP = posP + NSLOT * NROWS;

  knorm<<<NROWS / 4, 256, 0, stream>>>(emb, ebfB, (uint4*)ws);
  kmain<<<dim3(NSTRIPS, NROWS / BM), 256, 0, stream>>>(ebfB, cats, posP, sumP);
  kmerge<<<NROWS / 256, 256, 0, stream>>>(posP, sumP, accv, out);
}